// Round 1
// baseline (457.262 us; speedup 1.0000x reference)
//
#include <hip/hip_runtime.h>

#define N_NODES 50000
#define N_EDGES 800000
#define IN_F 64
#define HID 64
#define N_CLS 16

// ---------------------------------------------------------------------------
// Scatter layer 1: for each (edge, feature) add x[src][f] into agg1[dst][f].
// Lane f of a 64-lane group handles feature f of one edge -> the gather
// x[src*64+f] and scatter agg1[dst*64+f] are contiguous 256B per edge.
// Thread with f==0 also bumps the degree counter.
// ---------------------------------------------------------------------------
__global__ void scatter64_kernel(const int* __restrict__ src,
                                 const int* __restrict__ dst,
                                 const float* __restrict__ x,
                                 float* __restrict__ agg1,
                                 float* __restrict__ deg) {
    long long idx = (long long)blockIdx.x * blockDim.x + threadIdx.x;
    if (idx >= (long long)N_EDGES * 64) return;
    int e = (int)(idx >> 6);
    int f = (int)(idx & 63);
    int s = src[e];
    int d = dst[e];
    float v = x[s * 64 + f];
    atomicAdd(&agg1[d * 64 + f], v);
    if (f == 0) atomicAdd(&deg[d], 1.0f);
}

// ---------------------------------------------------------------------------
// Node update layer 1 (+ fused y2 = h @ W2_l precompute for layer 2):
// one 64-lane wave per node; lane j owns output feature j.
//   mean = agg1[n]/max(deg,1)
//   h[n][j] = relu( sum_k mean[k]*W1_l[k][j] + b1[j] + sum_k x[n][k]*W1_r[k][j] )
//   y2[n][j<16] = sum_k h[n][k]*W2_l[k][j]
// mean[k], x[k], h[k] are broadcast via __shfl (register-only, no LDS).
// ---------------------------------------------------------------------------
__global__ void node1_kernel(const float* __restrict__ x,
                             const float* __restrict__ agg1,
                             const float* __restrict__ deg,
                             const float* __restrict__ W1_l,
                             const float* __restrict__ b1,
                             const float* __restrict__ W1_r,
                             const float* __restrict__ W2_l,
                             float* __restrict__ h,
                             float* __restrict__ y2) {
    int n = blockIdx.x * 4 + (threadIdx.x >> 6);
    int j = threadIdx.x & 63;
    if (n >= N_NODES) return;

    float dn = deg[n];
    float rdeg = 1.0f / fmaxf(dn, 1.0f);
    float mv = agg1[n * 64 + j] * rdeg;   // mean, feature j
    float xv = x[n * 64 + j];             // self,  feature j

    float acc = b1[j];
    #pragma unroll
    for (int k = 0; k < 64; ++k) {
        float mk = __shfl(mv, k);
        float xk = __shfl(xv, k);
        acc = fmaf(mk, W1_l[k * 64 + j], acc);
        acc = fmaf(xk, W1_r[k * 64 + j], acc);
    }
    float hv = fmaxf(acc, 0.0f);
    h[n * 64 + j] = hv;

    // y2 = h @ W2_l  (64 -> 16); all lanes shuffle, lanes 0..15 accumulate/store
    float acc2 = 0.0f;
    #pragma unroll
    for (int k = 0; k < 64; ++k) {
        float hk = __shfl(hv, k);
        if (j < 16) acc2 = fmaf(hk, W2_l[k * 16 + j], acc2);
    }
    if (j < 16) y2[n * 16 + j] = acc2;
}

// ---------------------------------------------------------------------------
// Scatter layer 2: add y2[src][f] (16 feats) into agg2[dst][f].
// ---------------------------------------------------------------------------
__global__ void scatter16_kernel(const int* __restrict__ src,
                                 const int* __restrict__ dst,
                                 const float* __restrict__ y2,
                                 float* __restrict__ agg2) {
    long long idx = (long long)blockIdx.x * blockDim.x + threadIdx.x;
    if (idx >= (long long)N_EDGES * 16) return;
    int e = (int)(idx >> 4);
    int f = (int)(idx & 15);
    float v = y2[src[e] * 16 + f];
    atomicAdd(&agg2[dst[e] * 16 + f], v);
}

// ---------------------------------------------------------------------------
// Node update layer 2: out[n][j] = agg2[n][j]/max(deg,1) + b2[j]
//                                  + sum_k h[n][k]*W2_r[k][j]
// 16 threads per node (flat indexing), h row is broadcast within the group.
// ---------------------------------------------------------------------------
__global__ void node2_kernel(const float* __restrict__ h,
                             const float* __restrict__ agg2,
                             const float* __restrict__ deg,
                             const float* __restrict__ W2_r,
                             const float* __restrict__ b2,
                             float* __restrict__ out) {
    int idx = blockIdx.x * blockDim.x + threadIdx.x;
    if (idx >= N_NODES * 16) return;
    int n = idx >> 4;
    int j = idx & 15;

    float rdeg = 1.0f / fmaxf(deg[n], 1.0f);
    float acc = agg2[idx] * rdeg + b2[j];
    #pragma unroll
    for (int k = 0; k < 64; ++k) {
        acc = fmaf(h[n * 64 + k], W2_r[k * 16 + j], acc);
    }
    out[idx] = acc;
}

extern "C" void kernel_launch(void* const* d_in, const int* in_sizes, int n_in,
                              void* d_out, int out_size, void* d_ws, size_t ws_size,
                              hipStream_t stream) {
    const float* x    = (const float*)d_in[0];
    const int*   ei   = (const int*)d_in[1];   // [2, 800000]: row 0 = src, row 1 = dst
    const float* W1_l = (const float*)d_in[2];
    const float* b1   = (const float*)d_in[3];
    const float* W1_r = (const float*)d_in[4];
    const float* W2_l = (const float*)d_in[5];
    const float* b2   = (const float*)d_in[6];
    const float* W2_r = (const float*)d_in[7];
    float* out = (float*)d_out;

    const int* src = ei;
    const int* dst = ei + N_EDGES;

    // Workspace layout (floats):
    float* ws   = (float*)d_ws;
    float* deg  = ws;                       // 50048 (padded)
    float* agg1 = deg  + 50048;             // 50000*64 = 3,200,000
    float* h    = agg1 + 3200000;           // 3,200,000
    float* y2   = h    + 3200000;           // 50000*16 = 800,000
    float* agg2 = y2   + 800000;            // 800,000
    // total ~32.2 MB

    // ws is poisoned with 0xAA before every timed launch -> zero the accumulators.
    hipMemsetAsync(deg,  0, 50048   * sizeof(float), stream);
    hipMemsetAsync(agg1, 0, 3200000 * sizeof(float), stream);
    hipMemsetAsync(agg2, 0, 800000  * sizeof(float), stream);

    {   // layer-1 scatter + degree
        long long total = (long long)N_EDGES * 64;
        int block = 256;
        int grid = (int)((total + block - 1) / block);
        scatter64_kernel<<<grid, block, 0, stream>>>(src, dst, x, agg1, deg);
    }
    {   // layer-1 node update + y2 precompute
        int grid = (N_NODES + 3) / 4;       // 4 nodes (waves) per 256-thread block
        node1_kernel<<<grid, 256, 0, stream>>>(x, agg1, deg, W1_l, b1, W1_r,
                                               W2_l, h, y2);
    }
    {   // layer-2 scatter (16 features thanks to transform-first)
        long long total = (long long)N_EDGES * 16;
        int block = 256;
        int grid = (int)((total + block - 1) / block);
        scatter16_kernel<<<grid, block, 0, stream>>>(src, dst, y2, agg2);
    }
    {   // layer-2 node update -> out
        int total = N_NODES * 16;
        int block = 256;
        int grid = (total + block - 1) / block;
        node2_kernel<<<grid, block, 0, stream>>>(h, agg2, deg, W2_r, b2, out);
    }
}

// Round 2
// 429.151 us; speedup vs baseline: 1.0655x; 1.0655x over previous
//
#include <hip/hip_runtime.h>

#define N_NODES 50000
#define N_EDGES 800000
#define IN_F 64
#define HID 64
#define N_CLS 16

// ---------------------------------------------------------------------------
// CSR build step 1: histogram of dst. Non-returning int atomics on a 200 KB
// counter array (L2-resident).
// ---------------------------------------------------------------------------
__global__ void hist_kernel(const int* __restrict__ dst, int* __restrict__ cnt) {
    int e = blockIdx.x * blockDim.x + threadIdx.x;
    if (e < N_EDGES) atomicAdd(&cnt[dst[e]], 1);
}

// ---------------------------------------------------------------------------
// CSR build step 2: exclusive scan of cnt -> rowptr[0..N], cursor copy.
// Single 1024-thread workgroup; each thread serially sums a 49-element chunk,
// Hillis-Steele scan of the 1024 partials in LDS, then serial write-out.
// ---------------------------------------------------------------------------
__global__ void scan_kernel(const int* __restrict__ cnt,
                            int* __restrict__ rowptr,
                            int* __restrict__ cursor) {
    __shared__ int sums[1024];
    const int CHUNK = (N_NODES + 1023) / 1024;   // 49
    int t = threadIdx.x;
    int start = t * CHUNK;
    int end = min(start + CHUNK, N_NODES);
    int s = 0;
    for (int i = start; i < end; ++i) s += cnt[i];
    sums[t] = s;
    __syncthreads();
    for (int off = 1; off < 1024; off <<= 1) {
        int v = 0;
        if (t >= off) v = sums[t - off];
        __syncthreads();
        if (t >= off) sums[t] += v;
        __syncthreads();
    }
    int run = (t == 0) ? 0 : sums[t - 1];
    for (int i = start; i < end; ++i) {
        rowptr[i] = run;
        cursor[i] = run;
        run += cnt[i];
    }
    if (t == 0) rowptr[N_NODES] = sums[1023];
}

// ---------------------------------------------------------------------------
// CSR build step 3: place each edge's src into its dst's segment.
// ---------------------------------------------------------------------------
__global__ void fill_kernel(const int* __restrict__ src,
                            const int* __restrict__ dst,
                            int* __restrict__ cursor,
                            int* __restrict__ csr_src) {
    int e = blockIdx.x * blockDim.x + threadIdx.x;
    if (e >= N_EDGES) return;
    int pos = atomicAdd(&cursor[dst[e]], 1);
    csr_src[pos] = src[e];
}

// ---------------------------------------------------------------------------
// Fused layer 1: one 64-lane wave per node, lane j = feature j.
//   mean[j] = (sum over CSR neighbors of x[s][j]) / max(deg,1)   [gather]
//   h[n][j] = relu( mean@W1_l + b1 + x[n]@W1_r )[j]              [shfl matmul]
//   y2[n][j<16] = (h[n] @ W2_l)[j]                               [pre-transform]
// No atomics; agg1 never materialized.
// ---------------------------------------------------------------------------
__global__ void layer1_kernel(const float* __restrict__ x,
                              const int* __restrict__ rowptr,
                              const int* __restrict__ csr_src,
                              const float* __restrict__ W1_l,
                              const float* __restrict__ b1,
                              const float* __restrict__ W1_r,
                              const float* __restrict__ W2_l,
                              float* __restrict__ h,
                              float* __restrict__ y2) {
    int n = blockIdx.x * 4 + (threadIdx.x >> 6);
    int j = threadIdx.x & 63;
    if (n >= N_NODES) return;

    int beg = rowptr[n];
    int end = rowptr[n + 1];

    float sum = 0.0f;
    int i = beg;
    for (; i + 3 < end; i += 4) {            // unroll-4: 4 independent gathers in flight
        int s0 = csr_src[i];
        int s1 = csr_src[i + 1];
        int s2 = csr_src[i + 2];
        int s3 = csr_src[i + 3];
        float v0 = x[s0 * 64 + j];
        float v1 = x[s1 * 64 + j];
        float v2 = x[s2 * 64 + j];
        float v3 = x[s3 * 64 + j];
        sum += (v0 + v1) + (v2 + v3);
    }
    for (; i < end; ++i) sum += x[csr_src[i] * 64 + j];

    float deg = (float)(end - beg);
    float mv = sum / fmaxf(deg, 1.0f);       // mean, feature j
    float xv = x[n * 64 + j];                // self,  feature j

    float acc = b1[j];
    #pragma unroll
    for (int k = 0; k < 64; ++k) {
        float mk = __shfl(mv, k);
        float xk = __shfl(xv, k);
        acc = fmaf(mk, W1_l[k * 64 + j], acc);
        acc = fmaf(xk, W1_r[k * 64 + j], acc);
    }
    float hv = fmaxf(acc, 0.0f);
    h[n * 64 + j] = hv;

    float acc2 = 0.0f;
    #pragma unroll
    for (int k = 0; k < 64; ++k) {
        float hk = __shfl(hv, k);
        if (j < 16) acc2 = fmaf(hk, W2_l[k * 16 + j], acc2);
    }
    if (j < 16) y2[n * 16 + j] = acc2;
}

// ---------------------------------------------------------------------------
// Fused layer 2: 16 lanes per node (4 nodes per wave).
//   out[n][j] = (gather-mean of y2 over neighbors)[j] + b2[j] + (h[n]@W2_r)[j]
// ---------------------------------------------------------------------------
__global__ void layer2_kernel(const float* __restrict__ h,
                              const float* __restrict__ y2,
                              const int* __restrict__ rowptr,
                              const int* __restrict__ csr_src,
                              const float* __restrict__ W2_r,
                              const float* __restrict__ b2,
                              float* __restrict__ out) {
    int idx = blockIdx.x * blockDim.x + threadIdx.x;
    int n = idx >> 4;
    int j = idx & 15;
    if (n >= N_NODES) return;

    int beg = rowptr[n];
    int end = rowptr[n + 1];

    float sum = 0.0f;
    int i = beg;
    for (; i + 3 < end; i += 4) {
        int s0 = csr_src[i];
        int s1 = csr_src[i + 1];
        int s2 = csr_src[i + 2];
        int s3 = csr_src[i + 3];
        float v0 = y2[s0 * 16 + j];
        float v1 = y2[s1 * 16 + j];
        float v2 = y2[s2 * 16 + j];
        float v3 = y2[s3 * 16 + j];
        sum += (v0 + v1) + (v2 + v3);
    }
    for (; i < end; ++i) sum += y2[csr_src[i] * 16 + j];

    float deg = (float)(end - beg);
    float acc = sum / fmaxf(deg, 1.0f) + b2[j];

    const float* hrow = h + n * 64;
    #pragma unroll
    for (int k = 0; k < 64; ++k) {
        acc = fmaf(hrow[k], W2_r[k * 16 + j], acc);
    }
    out[idx] = acc;
}

extern "C" void kernel_launch(void* const* d_in, const int* in_sizes, int n_in,
                              void* d_out, int out_size, void* d_ws, size_t ws_size,
                              hipStream_t stream) {
    const float* x    = (const float*)d_in[0];
    const int*   ei   = (const int*)d_in[1];   // [2, 800000]: row 0 = src, row 1 = dst
    const float* W1_l = (const float*)d_in[2];
    const float* b1   = (const float*)d_in[3];
    const float* W1_r = (const float*)d_in[4];
    const float* W2_l = (const float*)d_in[5];
    const float* b2   = (const float*)d_in[6];
    const float* W2_r = (const float*)d_in[7];
    float* out = (float*)d_out;

    const int* src = ei;
    const int* dst = ei + N_EDGES;

    // Workspace layout (4-byte units):
    int*   cnt     = (int*)d_ws;                 // 50,048
    int*   cursor  = cnt     + 50048;            // 50,048
    int*   rowptr  = cursor  + 50048;            // 50,048 (uses 50,001)
    int*   csr_src = rowptr  + 50048;            // 800,000
    float* h       = (float*)(csr_src + 800000); // 3,200,000
    float* y2      = h       + 3200000;          // 800,000
    // total ~20 MB

    hipMemsetAsync(cnt, 0, 50048 * sizeof(int), stream);

    {   // histogram
        int grid = (N_EDGES + 255) / 256;
        hist_kernel<<<grid, 256, 0, stream>>>(dst, cnt);
    }
    {   // scan -> rowptr, cursor
        scan_kernel<<<1, 1024, 0, stream>>>(cnt, rowptr, cursor);
    }
    {   // CSR fill
        int grid = (N_EDGES + 255) / 256;
        fill_kernel<<<grid, 256, 0, stream>>>(src, dst, cursor, csr_src);
    }
    {   // fused layer 1 (gather + node update + y2 pre-transform)
        int grid = (N_NODES + 3) / 4;
        layer1_kernel<<<grid, 256, 0, stream>>>(x, rowptr, csr_src,
                                                W1_l, b1, W1_r, W2_l, h, y2);
    }
    {   // fused layer 2 -> out
        int total = N_NODES * 16;
        int grid = (total + 255) / 256;
        layer2_kernel<<<grid, 256, 0, stream>>>(h, y2, rowptr, csr_src,
                                                W2_r, b2, out);
    }
}

// Round 3
// 358.054 us; speedup vs baseline: 1.2771x; 1.1986x over previous
//
#include <hip/hip_runtime.h>

#define N_NODES 50000
#define N_EDGES 800000

// ---------------------------------------------------------------------------
// CSR build step 1: histogram of dst (L2-resident int atomics).
// ---------------------------------------------------------------------------
__global__ void hist_kernel(const int* __restrict__ dst, int* __restrict__ cnt) {
    int e = blockIdx.x * blockDim.x + threadIdx.x;
    if (e < N_EDGES) atomicAdd(&cnt[dst[e]], 1);
}

// ---------------------------------------------------------------------------
// CSR build step 2: exclusive scan of cnt -> rowptr / cursor (single block).
// ---------------------------------------------------------------------------
__global__ void scan_kernel(const int* __restrict__ cnt,
                            int* __restrict__ rowptr,
                            int* __restrict__ cursor) {
    __shared__ int sums[1024];
    const int CHUNK = (N_NODES + 1023) / 1024;   // 49
    int t = threadIdx.x;
    int start = t * CHUNK;
    int end = min(start + CHUNK, N_NODES);
    int s = 0;
    for (int i = start; i < end; ++i) s += cnt[i];
    sums[t] = s;
    __syncthreads();
    for (int off = 1; off < 1024; off <<= 1) {
        int v = 0;
        if (t >= off) v = sums[t - off];
        __syncthreads();
        if (t >= off) sums[t] += v;
        __syncthreads();
    }
    int run = (t == 0) ? 0 : sums[t - 1];
    for (int i = start; i < end; ++i) {
        rowptr[i] = run;
        cursor[i] = run;
        run += cnt[i];
    }
    if (t == 0) rowptr[N_NODES] = sums[1023];
}

// ---------------------------------------------------------------------------
// CSR build step 3: place each edge's src into its dst segment.
// ---------------------------------------------------------------------------
__global__ void fill_kernel(const int* __restrict__ src,
                            const int* __restrict__ dst,
                            int* __restrict__ cursor,
                            int* __restrict__ csr_src) {
    int e = blockIdx.x * blockDim.x + threadIdx.x;
    if (e >= N_EDGES) return;
    int pos = atomicAdd(&cursor[dst[e]], 1);
    csr_src[pos] = src[e];
}

// ---------------------------------------------------------------------------
// Fused layer 1. One 64-lane wave per node (4 nodes / 256-block).
// Lane layout: c = lane&15 (feature chunk 4c..4c+3), g = lane>>4 (group).
//  - gather: each group pulls a different neighbor row as float4 -> one
//    wave-load covers 4 rows (1 KB); unroll x2 -> 8 rows in flight.
//  - cross-group reduce (shfl_xor 16,32) -> mean
//  - 64x64x2 matmul, k-range split across groups, float4 weight loads
//  - h kept in registers; y2 = h@W2_l and z = h@W2_r + b2 computed here.
//    h is NEVER written to memory.
// ---------------------------------------------------------------------------
__global__ __launch_bounds__(256) void layer1_kernel(
        const float* __restrict__ x,
        const int* __restrict__ rowptr,
        const int* __restrict__ csr_src,
        const float* __restrict__ W1_l,
        const float* __restrict__ b1,
        const float* __restrict__ W1_r,
        const float* __restrict__ W2_l,
        const float* __restrict__ W2_r,
        const float* __restrict__ b2,
        float* __restrict__ y2,
        float* __restrict__ z) {
    const int n = blockIdx.x * 4 + (threadIdx.x >> 6);   // 50000 % 4 == 0
    const int l = threadIdx.x & 63;
    const int c = l & 15;
    const int g = l >> 4;

    const int beg = rowptr[n];
    const int end = rowptr[n + 1];

    // ---- gather-mean of neighbor x rows ----
    float s0 = 0.f, s1 = 0.f, s2 = 0.f, s3 = 0.f;
    const float* xb = x + 4 * c;
    int i = beg + g;
    for (; i + 4 < end; i += 8) {
        int a = csr_src[i];
        int b = csr_src[i + 4];
        float4 va = *(const float4*)(xb + a * 64);
        float4 vb = *(const float4*)(xb + b * 64);
        s0 += va.x + vb.x; s1 += va.y + vb.y;
        s2 += va.z + vb.z; s3 += va.w + vb.w;
    }
    if (i < end) {
        int a = csr_src[i];
        float4 va = *(const float4*)(xb + a * 64);
        s0 += va.x; s1 += va.y; s2 += va.z; s3 += va.w;
    }
    // cross-group reduction: every lane ends with the full sum for chunk c
    s0 += __shfl_xor(s0, 16); s0 += __shfl_xor(s0, 32);
    s1 += __shfl_xor(s1, 16); s1 += __shfl_xor(s1, 32);
    s2 += __shfl_xor(s2, 16); s2 += __shfl_xor(s2, 32);
    s3 += __shfl_xor(s3, 16); s3 += __shfl_xor(s3, 32);

    const float rdeg = 1.0f / fmaxf((float)(end - beg), 1.0f);
    float m[4] = { s0 * rdeg, s1 * rdeg, s2 * rdeg, s3 * rdeg };
    float4 xv4 = *(const float4*)(x + n * 64 + 4 * c);
    float xs[4] = { xv4.x, xv4.y, xv4.z, xv4.w };

    // ---- acc = mean@W1_l + x@W1_r, k split across groups ----
    float a0 = 0.f, a1 = 0.f, a2 = 0.f, a3 = 0.f;
    #pragma unroll
    for (int kk = 0; kk < 16; ++kk) {
        const int k = 16 * g + kk;
        const int srclane = 4 * g + (kk >> 2);
        const float mk = __shfl(m[kk & 3], srclane);
        const float xk = __shfl(xs[kk & 3], srclane);
        const float4 wl = *(const float4*)(W1_l + k * 64 + 4 * c);
        const float4 wr = *(const float4*)(W1_r + k * 64 + 4 * c);
        a0 = fmaf(mk, wl.x, a0); a0 = fmaf(xk, wr.x, a0);
        a1 = fmaf(mk, wl.y, a1); a1 = fmaf(xk, wr.y, a1);
        a2 = fmaf(mk, wl.z, a2); a2 = fmaf(xk, wr.z, a2);
        a3 = fmaf(mk, wl.w, a3); a3 = fmaf(xk, wr.w, a3);
    }
    a0 += __shfl_xor(a0, 16); a0 += __shfl_xor(a0, 32);
    a1 += __shfl_xor(a1, 16); a1 += __shfl_xor(a1, 32);
    a2 += __shfl_xor(a2, 16); a2 += __shfl_xor(a2, 32);
    a3 += __shfl_xor(a3, 16); a3 += __shfl_xor(a3, 32);

    const float4 bb = *(const float4*)(b1 + 4 * c);
    float h[4] = { fmaxf(a0 + bb.x, 0.f), fmaxf(a1 + bb.y, 0.f),
                   fmaxf(a2 + bb.z, 0.f), fmaxf(a3 + bb.w, 0.f) };

    // ---- y2 = h@W2_l, z = h@W2_r + b2 (64 -> 16 each) ----
    // lane: oc = l&3 (output chunk), seg = l>>2 (k segment, k in [4seg,4seg+4))
    const int oc = l & 3;
    const int seg = l >> 2;
    float p0 = 0.f, p1 = 0.f, p2 = 0.f, p3 = 0.f;   // y2
    float q0 = 0.f, q1 = 0.f, q2 = 0.f, q3 = 0.f;   // z
    #pragma unroll
    for (int q = 0; q < 4; ++q) {
        const int k = 4 * seg + q;
        const float hk = __shfl(h[q], seg);          // lane seg holds chunk seg
        const float4 w2l = *(const float4*)(W2_l + k * 16 + 4 * oc);
        const float4 w2r = *(const float4*)(W2_r + k * 16 + 4 * oc);
        p0 = fmaf(hk, w2l.x, p0); q0 = fmaf(hk, w2r.x, q0);
        p1 = fmaf(hk, w2l.y, p1); q1 = fmaf(hk, w2r.y, q1);
        p2 = fmaf(hk, w2l.z, p2); q2 = fmaf(hk, w2r.z, q2);
        p3 = fmaf(hk, w2l.w, p3); q3 = fmaf(hk, w2r.w, q3);
    }
    p0 += __shfl_xor(p0, 4); p0 += __shfl_xor(p0, 8); p0 += __shfl_xor(p0, 16); p0 += __shfl_xor(p0, 32);
    p1 += __shfl_xor(p1, 4); p1 += __shfl_xor(p1, 8); p1 += __shfl_xor(p1, 16); p1 += __shfl_xor(p1, 32);
    p2 += __shfl_xor(p2, 4); p2 += __shfl_xor(p2, 8); p2 += __shfl_xor(p2, 16); p2 += __shfl_xor(p2, 32);
    p3 += __shfl_xor(p3, 4); p3 += __shfl_xor(p3, 8); p3 += __shfl_xor(p3, 16); p3 += __shfl_xor(p3, 32);
    q0 += __shfl_xor(q0, 4); q0 += __shfl_xor(q0, 8); q0 += __shfl_xor(q0, 16); q0 += __shfl_xor(q0, 32);
    q1 += __shfl_xor(q1, 4); q1 += __shfl_xor(q1, 8); q1 += __shfl_xor(q1, 16); q1 += __shfl_xor(q1, 32);
    q2 += __shfl_xor(q2, 4); q2 += __shfl_xor(q2, 8); q2 += __shfl_xor(q2, 16); q2 += __shfl_xor(q2, 32);
    q3 += __shfl_xor(q3, 4); q3 += __shfl_xor(q3, 8); q3 += __shfl_xor(q3, 16); q3 += __shfl_xor(q3, 32);

    if (l < 4) {   // oc == l, seg == 0
        float4 y4 = { p0, p1, p2, p3 };
        *(float4*)(y2 + n * 16 + 4 * l) = y4;
        const float4 b2v = *(const float4*)(b2 + 4 * l);
        float4 z4 = { q0 + b2v.x, q1 + b2v.y, q2 + b2v.z, q3 + b2v.w };
        *(float4*)(z + n * 16 + 4 * l) = z4;
    }
}

// ---------------------------------------------------------------------------
// Fused layer 2: pure gather-mean of y2 + z. 16 lanes per node
// (p = t>>2 neighbor subgroup, c = t&3 feature chunk), 4 nodes per wave.
// ---------------------------------------------------------------------------
__global__ __launch_bounds__(256) void layer2_kernel(
        const float* __restrict__ y2,
        const float* __restrict__ z,
        const int* __restrict__ rowptr,
        const int* __restrict__ csr_src,
        float* __restrict__ out) {
    const int wave = blockIdx.x * 4 + (threadIdx.x >> 6);
    const int l = threadIdx.x & 63;
    const int n = wave * 4 + (l >> 4);   // 50000 = 3125 blocks * 16 nodes
    const int t = l & 15;
    const int p = t >> 2;
    const int c = t & 3;

    const int beg = rowptr[n];
    const int end = rowptr[n + 1];

    float s0 = 0.f, s1 = 0.f, s2 = 0.f, s3 = 0.f;
    const float* yb = y2 + 4 * c;
    int i = beg + p;
    for (; i + 4 < end; i += 8) {
        int a = csr_src[i];
        int b = csr_src[i + 4];
        float4 va = *(const float4*)(yb + a * 16);
        float4 vb = *(const float4*)(yb + b * 16);
        s0 += va.x + vb.x; s1 += va.y + vb.y;
        s2 += va.z + vb.z; s3 += va.w + vb.w;
    }
    if (i < end) {
        int a = csr_src[i];
        float4 va = *(const float4*)(yb + a * 16);
        s0 += va.x; s1 += va.y; s2 += va.z; s3 += va.w;
    }
    // reduce across the 4 neighbor subgroups (stays within the 16-lane node)
    s0 += __shfl_xor(s0, 4); s0 += __shfl_xor(s0, 8);
    s1 += __shfl_xor(s1, 4); s1 += __shfl_xor(s1, 8);
    s2 += __shfl_xor(s2, 4); s2 += __shfl_xor(s2, 8);
    s3 += __shfl_xor(s3, 4); s3 += __shfl_xor(s3, 8);

    if (p == 0) {
        const float rdeg = 1.0f / fmaxf((float)(end - beg), 1.0f);
        const float4 zv = *(const float4*)(z + n * 16 + 4 * c);
        float4 o = { s0 * rdeg + zv.x, s1 * rdeg + zv.y,
                     s2 * rdeg + zv.z, s3 * rdeg + zv.w };
        *(float4*)(out + n * 16 + 4 * c) = o;
    }
}

extern "C" void kernel_launch(void* const* d_in, const int* in_sizes, int n_in,
                              void* d_out, int out_size, void* d_ws, size_t ws_size,
                              hipStream_t stream) {
    const float* x    = (const float*)d_in[0];
    const int*   ei   = (const int*)d_in[1];   // [2, 800000]: row 0 = src, row 1 = dst
    const float* W1_l = (const float*)d_in[2];
    const float* b1   = (const float*)d_in[3];
    const float* W1_r = (const float*)d_in[4];
    const float* W2_l = (const float*)d_in[5];
    const float* b2   = (const float*)d_in[6];
    const float* W2_r = (const float*)d_in[7];
    float* out = (float*)d_out;

    const int* src = ei;
    const int* dst = ei + N_EDGES;

    // Workspace layout (4-byte units):
    int*   cnt     = (int*)d_ws;                 // 50,048
    int*   cursor  = cnt     + 50048;            // 50,048
    int*   rowptr  = cursor  + 50048;            // 50,048 (uses 50,001)
    int*   csr_src = rowptr  + 50048;            // 800,000
    float* y2      = (float*)(csr_src + 800000); // 800,000
    float* z       = y2      + 800000;           // 800,000
    // total ~10 MB

    hipMemsetAsync(cnt, 0, 50048 * sizeof(int), stream);

    hist_kernel<<<(N_EDGES + 255) / 256, 256, 0, stream>>>(dst, cnt);
    scan_kernel<<<1, 1024, 0, stream>>>(cnt, rowptr, cursor);
    fill_kernel<<<(N_EDGES + 255) / 256, 256, 0, stream>>>(src, dst, cursor, csr_src);
    layer1_kernel<<<N_NODES / 4, 256, 0, stream>>>(x, rowptr, csr_src,
                                                   W1_l, b1, W1_r,
                                                   W2_l, W2_r, b2, y2, z);
    layer2_kernel<<<N_NODES / 16, 256, 0, stream>>>(y2, z, rowptr, csr_src, out);
}

// Round 4
// 256.710 us; speedup vs baseline: 1.7812x; 1.3948x over previous
//
#include <hip/hip_runtime.h>

#define N_NODES 50000
#define N_EDGES 800000
#define PAD_N   51200          // 50 blocks' worth of padding (>= 49*1024)
#define SCAN_BLOCKS 49         // 49 * 1024 = 50176 >= N_NODES+1

// ---------------------------------------------------------------------------
// CSR build step 1: histogram of dst (L2-resident int atomics), 4 edges/thread.
// ---------------------------------------------------------------------------
__global__ void hist_kernel(const int* __restrict__ dst, int* __restrict__ cnt) {
    int e4 = blockIdx.x * blockDim.x + threadIdx.x;
    if (e4 >= N_EDGES / 4) return;
    int4 d = *(const int4*)(dst + e4 * 4);
    atomicAdd(&cnt[d.x], 1);
    atomicAdd(&cnt[d.y], 1);
    atomicAdd(&cnt[d.z], 1);
    atomicAdd(&cnt[d.w], 1);
}

// ---------------------------------------------------------------------------
// Device-wide exclusive scan, step A: each block scans a 1024-element chunk
// (256 threads x int4). Writes per-element local exclusive scan to `loc`
// and the block total to bsum[b]. cnt is zero-padded to PAD_N, so no guards.
// ---------------------------------------------------------------------------
__global__ void scanA_kernel(const int* __restrict__ cnt,
                             int* __restrict__ loc,
                             int* __restrict__ bsum) {
    __shared__ int lds[256];
    const int b = blockIdx.x, t = threadIdx.x;
    const int base = b * 1024 + t * 4;
    int4 v = *(const int4*)(cnt + base);
    const int s = v.x + v.y + v.z + v.w;
    lds[t] = s;
    __syncthreads();
    for (int off = 1; off < 256; off <<= 1) {
        int u = (t >= off) ? lds[t - off] : 0;
        __syncthreads();
        lds[t] += u;
        __syncthreads();
    }
    const int excl = lds[t] - s;   // exclusive prefix of this thread's 4 elems
    int4 o;
    o.x = excl;
    o.y = excl + v.x;
    o.z = excl + v.x + v.y;
    o.w = excl + v.x + v.y + v.z;
    *(int4*)(loc + base) = o;
    if (t == 255) bsum[b] = lds[255];
}

// ---------------------------------------------------------------------------
// Scan step B: one wave shfl-scans the 49 block sums -> exclusive offsets.
// ---------------------------------------------------------------------------
__global__ void scanB_kernel(int* __restrict__ bsum) {
    const int t = threadIdx.x;           // 64 threads
    int v = (t < SCAN_BLOCKS) ? bsum[t] : 0;
    const int orig = v;
    for (int off = 1; off < 64; off <<= 1) {
        int u = __shfl_up(v, off);
        if (t >= off) v += u;
    }
    if (t < SCAN_BLOCKS) bsum[t] = v - orig;   // exclusive block offset
}

// ---------------------------------------------------------------------------
// Scan step C: add block offset, emit rowptr and cursor (int4 coalesced).
// rowptr[N_NODES] = total (=800000) falls out naturally from the padded zeros.
// ---------------------------------------------------------------------------
__global__ void scanC_kernel(const int* __restrict__ loc,
                             const int* __restrict__ bsum,
                             int* __restrict__ rowptr,
                             int* __restrict__ cursor) {
    const int b = blockIdx.x, t = threadIdx.x;
    const int base = b * 1024 + t * 4;
    const int off = bsum[b];
    int4 v = *(const int4*)(loc + base);
    v.x += off; v.y += off; v.z += off; v.w += off;
    *(int4*)(rowptr + base) = v;
    *(int4*)(cursor + base) = v;
}

// ---------------------------------------------------------------------------
// CSR build step 3: place each edge's src into its dst segment.
// ---------------------------------------------------------------------------
__global__ void fill_kernel(const int* __restrict__ src,
                            const int* __restrict__ dst,
                            int* __restrict__ cursor,
                            int* __restrict__ csr_src) {
    int e = blockIdx.x * blockDim.x + threadIdx.x;
    if (e >= N_EDGES) return;
    int pos = atomicAdd(&cursor[dst[e]], 1);
    csr_src[pos] = src[e];
}

// ---------------------------------------------------------------------------
// Fused layer 1. One 64-lane wave per node (4 nodes / 256-block).
// Lane layout: c = lane&15 (feature chunk 4c..4c+3), g = lane>>4 (group).
//  - gather: each group pulls a different neighbor row as float4 -> one
//    wave-load covers 4 rows (1 KB); unroll x2 -> 8 rows in flight.
//  - cross-group reduce (shfl_xor 16,32) -> mean
//  - 64x64x2 matmul, k-range split across groups, float4 weight loads
//  - h kept in registers; y2 = h@W2_l and z = h@W2_r + b2 computed here.
//    h is NEVER written to memory.
// ---------------------------------------------------------------------------
__global__ __launch_bounds__(256) void layer1_kernel(
        const float* __restrict__ x,
        const int* __restrict__ rowptr,
        const int* __restrict__ csr_src,
        const float* __restrict__ W1_l,
        const float* __restrict__ b1,
        const float* __restrict__ W1_r,
        const float* __restrict__ W2_l,
        const float* __restrict__ W2_r,
        const float* __restrict__ b2,
        float* __restrict__ y2,
        float* __restrict__ z) {
    const int n = blockIdx.x * 4 + (threadIdx.x >> 6);   // 50000 % 4 == 0
    const int l = threadIdx.x & 63;
    const int c = l & 15;
    const int g = l >> 4;

    const int beg = rowptr[n];
    const int end = rowptr[n + 1];

    // ---- gather-mean of neighbor x rows ----
    float s0 = 0.f, s1 = 0.f, s2 = 0.f, s3 = 0.f;
    const float* xb = x + 4 * c;
    int i = beg + g;
    for (; i + 4 < end; i += 8) {
        int a = csr_src[i];
        int b = csr_src[i + 4];
        float4 va = *(const float4*)(xb + a * 64);
        float4 vb = *(const float4*)(xb + b * 64);
        s0 += va.x + vb.x; s1 += va.y + vb.y;
        s2 += va.z + vb.z; s3 += va.w + vb.w;
    }
    if (i < end) {
        int a = csr_src[i];
        float4 va = *(const float4*)(xb + a * 64);
        s0 += va.x; s1 += va.y; s2 += va.z; s3 += va.w;
    }
    // cross-group reduction: every lane ends with the full sum for chunk c
    s0 += __shfl_xor(s0, 16); s0 += __shfl_xor(s0, 32);
    s1 += __shfl_xor(s1, 16); s1 += __shfl_xor(s1, 32);
    s2 += __shfl_xor(s2, 16); s2 += __shfl_xor(s2, 32);
    s3 += __shfl_xor(s3, 16); s3 += __shfl_xor(s3, 32);

    const float rdeg = 1.0f / fmaxf((float)(end - beg), 1.0f);
    float m[4] = { s0 * rdeg, s1 * rdeg, s2 * rdeg, s3 * rdeg };
    float4 xv4 = *(const float4*)(x + n * 64 + 4 * c);
    float xs[4] = { xv4.x, xv4.y, xv4.z, xv4.w };

    // ---- acc = mean@W1_l + x@W1_r, k split across groups ----
    float a0 = 0.f, a1 = 0.f, a2 = 0.f, a3 = 0.f;
    #pragma unroll
    for (int kk = 0; kk < 16; ++kk) {
        const int k = 16 * g + kk;
        const int srclane = 4 * g + (kk >> 2);
        const float mk = __shfl(m[kk & 3], srclane);
        const float xk = __shfl(xs[kk & 3], srclane);
        const float4 wl = *(const float4*)(W1_l + k * 64 + 4 * c);
        const float4 wr = *(const float4*)(W1_r + k * 64 + 4 * c);
        a0 = fmaf(mk, wl.x, a0); a0 = fmaf(xk, wr.x, a0);
        a1 = fmaf(mk, wl.y, a1); a1 = fmaf(xk, wr.y, a1);
        a2 = fmaf(mk, wl.z, a2); a2 = fmaf(xk, wr.z, a2);
        a3 = fmaf(mk, wl.w, a3); a3 = fmaf(xk, wr.w, a3);
    }
    a0 += __shfl_xor(a0, 16); a0 += __shfl_xor(a0, 32);
    a1 += __shfl_xor(a1, 16); a1 += __shfl_xor(a1, 32);
    a2 += __shfl_xor(a2, 16); a2 += __shfl_xor(a2, 32);
    a3 += __shfl_xor(a3, 16); a3 += __shfl_xor(a3, 32);

    const float4 bb = *(const float4*)(b1 + 4 * c);
    float h[4] = { fmaxf(a0 + bb.x, 0.f), fmaxf(a1 + bb.y, 0.f),
                   fmaxf(a2 + bb.z, 0.f), fmaxf(a3 + bb.w, 0.f) };

    // ---- y2 = h@W2_l, z = h@W2_r + b2 (64 -> 16 each) ----
    const int oc = l & 3;
    const int seg = l >> 2;
    float p0 = 0.f, p1 = 0.f, p2 = 0.f, p3 = 0.f;   // y2
    float q0 = 0.f, q1 = 0.f, q2 = 0.f, q3 = 0.f;   // z
    #pragma unroll
    for (int q = 0; q < 4; ++q) {
        const int k = 4 * seg + q;
        const float hk = __shfl(h[q], seg);          // lane seg holds chunk seg
        const float4 w2l = *(const float4*)(W2_l + k * 16 + 4 * oc);
        const float4 w2r = *(const float4*)(W2_r + k * 16 + 4 * oc);
        p0 = fmaf(hk, w2l.x, p0); q0 = fmaf(hk, w2r.x, q0);
        p1 = fmaf(hk, w2l.y, p1); q1 = fmaf(hk, w2r.y, q1);
        p2 = fmaf(hk, w2l.z, p2); q2 = fmaf(hk, w2r.z, q2);
        p3 = fmaf(hk, w2l.w, p3); q3 = fmaf(hk, w2r.w, q3);
    }
    p0 += __shfl_xor(p0, 4); p0 += __shfl_xor(p0, 8); p0 += __shfl_xor(p0, 16); p0 += __shfl_xor(p0, 32);
    p1 += __shfl_xor(p1, 4); p1 += __shfl_xor(p1, 8); p1 += __shfl_xor(p1, 16); p1 += __shfl_xor(p1, 32);
    p2 += __shfl_xor(p2, 4); p2 += __shfl_xor(p2, 8); p2 += __shfl_xor(p2, 16); p2 += __shfl_xor(p2, 32);
    p3 += __shfl_xor(p3, 4); p3 += __shfl_xor(p3, 8); p3 += __shfl_xor(p3, 16); p3 += __shfl_xor(p3, 32);
    q0 += __shfl_xor(q0, 4); q0 += __shfl_xor(q0, 8); q0 += __shfl_xor(q0, 16); q0 += __shfl_xor(q0, 32);
    q1 += __shfl_xor(q1, 4); q1 += __shfl_xor(q1, 8); q1 += __shfl_xor(q1, 16); q1 += __shfl_xor(q1, 32);
    q2 += __shfl_xor(q2, 4); q2 += __shfl_xor(q2, 8); q2 += __shfl_xor(q2, 16); q2 += __shfl_xor(q2, 32);
    q3 += __shfl_xor(q3, 4); q3 += __shfl_xor(q3, 8); q3 += __shfl_xor(q3, 16); q3 += __shfl_xor(q3, 32);

    if (l < 4) {   // oc == l, seg == 0
        float4 y4 = { p0, p1, p2, p3 };
        *(float4*)(y2 + n * 16 + 4 * l) = y4;
        const float4 b2v = *(const float4*)(b2 + 4 * l);
        float4 z4 = { q0 + b2v.x, q1 + b2v.y, q2 + b2v.z, q3 + b2v.w };
        *(float4*)(z + n * 16 + 4 * l) = z4;
    }
}

// ---------------------------------------------------------------------------
// Fused layer 2: pure gather-mean of y2 + z. 16 lanes per node
// (p = t>>2 neighbor subgroup, c = t&3 feature chunk), 4 nodes per wave.
// ---------------------------------------------------------------------------
__global__ __launch_bounds__(256) void layer2_kernel(
        const float* __restrict__ y2,
        const float* __restrict__ z,
        const int* __restrict__ rowptr,
        const int* __restrict__ csr_src,
        float* __restrict__ out) {
    const int wave = blockIdx.x * 4 + (threadIdx.x >> 6);
    const int l = threadIdx.x & 63;
    const int n = wave * 4 + (l >> 4);   // 50000 = 3125 blocks * 16 nodes
    const int t = l & 15;
    const int p = t >> 2;
    const int c = t & 3;

    const int beg = rowptr[n];
    const int end = rowptr[n + 1];

    float s0 = 0.f, s1 = 0.f, s2 = 0.f, s3 = 0.f;
    const float* yb = y2 + 4 * c;
    int i = beg + p;
    for (; i + 4 < end; i += 8) {
        int a = csr_src[i];
        int b = csr_src[i + 4];
        float4 va = *(const float4*)(yb + a * 16);
        float4 vb = *(const float4*)(yb + b * 16);
        s0 += va.x + vb.x; s1 += va.y + vb.y;
        s2 += va.z + vb.z; s3 += va.w + vb.w;
    }
    if (i < end) {
        int a = csr_src[i];
        float4 va = *(const float4*)(yb + a * 16);
        s0 += va.x; s1 += va.y; s2 += va.z; s3 += va.w;
    }
    s0 += __shfl_xor(s0, 4); s0 += __shfl_xor(s0, 8);
    s1 += __shfl_xor(s1, 4); s1 += __shfl_xor(s1, 8);
    s2 += __shfl_xor(s2, 4); s2 += __shfl_xor(s2, 8);
    s3 += __shfl_xor(s3, 4); s3 += __shfl_xor(s3, 8);

    if (p == 0) {
        const float rdeg = 1.0f / fmaxf((float)(end - beg), 1.0f);
        const float4 zv = *(const float4*)(z + n * 16 + 4 * c);
        float4 o = { s0 * rdeg + zv.x, s1 * rdeg + zv.y,
                     s2 * rdeg + zv.z, s3 * rdeg + zv.w };
        *(float4*)(out + n * 16 + 4 * c) = o;
    }
}

extern "C" void kernel_launch(void* const* d_in, const int* in_sizes, int n_in,
                              void* d_out, int out_size, void* d_ws, size_t ws_size,
                              hipStream_t stream) {
    const float* x    = (const float*)d_in[0];
    const int*   ei   = (const int*)d_in[1];   // [2, 800000]: row 0 = src, row 1 = dst
    const float* W1_l = (const float*)d_in[2];
    const float* b1   = (const float*)d_in[3];
    const float* W1_r = (const float*)d_in[4];
    const float* W2_l = (const float*)d_in[5];
    const float* b2   = (const float*)d_in[6];
    const float* W2_r = (const float*)d_in[7];
    float* out = (float*)d_out;

    const int* src = ei;
    const int* dst = ei + N_EDGES;

    // Workspace layout (4-byte units), scan arrays padded to PAD_N:
    int*   cnt     = (int*)d_ws;                 // PAD_N (zeroed, incl. tail)
    int*   loc     = cnt     + PAD_N;            // PAD_N
    int*   rowptr  = loc     + PAD_N;            // PAD_N
    int*   cursor  = rowptr  + PAD_N;            // PAD_N
    int*   bsum    = cursor  + PAD_N;            // 64
    int*   csr_src = bsum    + 64;               // 800,000
    float* y2      = (float*)(csr_src + 800000); // 800,000
    float* z       = y2      + 800000;           // 800,000
    // total ~10.4 MB

    hipMemsetAsync(cnt, 0, PAD_N * sizeof(int), stream);

    hist_kernel<<<(N_EDGES / 4 + 255) / 256, 256, 0, stream>>>(dst, cnt);
    scanA_kernel<<<SCAN_BLOCKS, 256, 0, stream>>>(cnt, loc, bsum);
    scanB_kernel<<<1, 64, 0, stream>>>(bsum);
    scanC_kernel<<<SCAN_BLOCKS, 256, 0, stream>>>(loc, bsum, rowptr, cursor);
    fill_kernel<<<(N_EDGES + 255) / 256, 256, 0, stream>>>(src, dst, cursor, csr_src);
    layer1_kernel<<<N_NODES / 4, 256, 0, stream>>>(x, rowptr, csr_src,
                                                   W1_l, b1, W1_r,
                                                   W2_l, W2_r, b2, y2, z);
    layer2_kernel<<<N_NODES / 16, 256, 0, stream>>>(y2, z, rowptr, csr_src, out);
}